// Round 10
// baseline (59.619 us; speedup 1.0000x reference)
//
#include <hip/hip_runtime.h>
#include <hip/hip_bf16.h>
#include <math.h>

#define NROW 8192
#define DIM  128
#define BM   64
#define BN   128
#define NTILES 4160         // sum_{tr<128} (64 - (tr>>1))
#define NT4    (NTILES * 4) // per-wave results = 16640 = 32 * 520
#define NRED   32
#define PERRED (NT4 / NRED) // 520

typedef __bf16 bf16x8 __attribute__((ext_vector_type(8)));
typedef float  f32x4  __attribute__((ext_vector_type(4)));

#define G2     369.3299304675746f   /* 256 * log2(e): logits in base-2 */
#define QPOS   (0.9375f * G2)       /* xp = G2*s^2 - 2*G2*s + QPOS      */
#define QNEG   (-0.0625f * G2)      /* xn = G2*t^2 + QNEG, t=max(s,-.25)*/
#define NEGBIG (-3.0e38f)
#define MSENT  (-4000.0f)           /* empty-class sentinel */
#define CSTR   32                   /* cursor stride: 1 counter / 128B  */

// ---- Kernel H: label histogram + exclusive prefix -> padded cursor ----
__global__ __launch_bounds__(256)
void hist_kernel(const int* __restrict__ lab, int* __restrict__ cursor) {
    __shared__ int h[4][64];
    const int tid  = threadIdx.x;
    const int w    = tid >> 6;
    const int lane = tid & 63;
    h[w][lane] = 0;
    __syncthreads();
    for (int i = tid; i < NROW; i += 256)
        atomicAdd(&h[w][lab[i]], 1);
    __syncthreads();
    if (tid < 64) {
        int tot = h[0][tid] + h[1][tid] + h[2][tid] + h[3][tid];
        int v = tot;
        #pragma unroll
        for (int off = 1; off < 64; off <<= 1) {
            int u = __shfl_up(v, off, 64);
            if (tid >= off) v += u;
        }
        cursor[tid * CSTR] = v - tot;   // exclusive prefix, cacheline-padded
    }
}

// ---- Kernel A: normalize rows -> bf16, scattered into label-sorted order ----
__global__ __launch_bounds__(256)
void prep_kernel(const float* __restrict__ f, const int* __restrict__ lab,
                 int* __restrict__ cursor,
                 __hip_bfloat16* __restrict__ fhi, int* __restrict__ labS) {
    int row  = blockIdx.x * 4 + (threadIdx.x >> 6);
    int lane = threadIdx.x & 63;
    float2 v = ((const float2*)(f + (size_t)row * DIM))[lane];
    float ss = v.x * v.x + v.y * v.y;
    #pragma unroll
    for (int off = 32; off; off >>= 1) ss += __shfl_xor(ss, off, 64);
    float inv = 1.0f / fmaxf(sqrtf(ss), 1e-12f);
    int l = lab[row];
    int dest = 0;
    if (lane == 0) dest = atomicAdd(&cursor[l * CSTR], 1);
    dest = __shfl(dest, 0, 64);
    __hip_bfloat162 hv;
    hv.x = __float2bfloat16(v.x * inv);
    hv.y = __float2bfloat16(v.y * inv);
    ((__hip_bfloat162*)(fhi + (size_t)dest * DIM))[lane] = hv;
    if (lane == 0) labS[dest] = l;
}

// first linear bid of row-tile tr (tc starts at tr>>1)
__device__ __forceinline__ int tstart(int tr) {
    int m = tr >> 1;
    int f = m * m - ((tr & 1) ? 0 : m);
    return 64 * tr - f;
}

// ---- Kernel B: one tile/block; A in regs, B via LDS, ONE barrier ----
__global__ __launch_bounds__(256, 4)
void sim_kernel(const __hip_bfloat16* __restrict__ fhi,
                const int* __restrict__ labS,
                float4* __restrict__ blockRes) {
    const int tid  = threadIdx.x;
    const int w    = tid >> 6;
    const int lane = tid & 63;
    const int lrow = lane & 15;
    const int lk   = lane >> 4;

    // triangular decode: bid -> (tr, tc), tc >= tr>>1
    int bid = blockIdx.x;
    float sa = fmaxf(16384.f - 4.f * (float)bid, 0.f);
    int tr = 128 - (int)sqrtf(sa);
    if (tr > 127) tr = 127;
    if (tr < 0) tr = 0;
    while (tr > 0 && bid < tstart(tr)) --tr;
    while (bid >= tstart(tr + 1)) ++tr;
    const int tc = (tr >> 1) + (bid - tstart(tr));

    const int rowBase = tr * BM;
    const int colBase = tc * BN;

    __shared__ __align__(16) char smem[32 * 1024];   // B[128 rows][256 B]

    // ---- stage B (full K) via global_load_lds: 8 x 1KB segments / wave ----
    // seg covers 4 rows x 256B; LDS linear = row-major; source col pre-swizzled
    {
        const int rsub4 = lane >> 4;                 // row within 4-row segment
        const int col   = (lane & 15) << 4;          // 16B slot
        #pragma unroll
        for (int t = 0; t < 8; ++t) {
            int seg = w * 8 + t;                     // 0..31
            int row8 = ((seg & 1) << 2) + rsub4;     // (4*seg + rsub4) & 7
            char* ldsb = smem + seg * 1024;
            int grow = colBase + seg * 4 + rsub4;
            const char* g = (const char*)fhi + (size_t)grow * 256
                          + (col ^ (row8 << 4));
            __builtin_amdgcn_global_load_lds(
                (const __attribute__((address_space(1))) void*)g,
                (__attribute__((address_space(3))) void*)ldsb, 16, 0, 0);
        }
    }

    // ---- A fragments direct global -> registers (16 x 16B per lane) ----
    bf16x8 areg[4][4];   // [mi][q], q = K-step of 32
    {
        const char* abase = (const char*)fhi
            + (size_t)(rowBase + lrow) * 256 + lk * 16;
        #pragma unroll
        for (int mi = 0; mi < 4; ++mi)
            #pragma unroll
            for (int q = 0; q < 4; ++q)
                areg[mi][q] = *(const bf16x8*)(abase + mi * (16 * 256) + q * 64);
    }

    f32x4 acc[4][2];
    #pragma unroll
    for (int mi = 0; mi < 4; ++mi)
        #pragma unroll
        for (int ni = 0; ni < 2; ++ni) acc[mi][ni] = (f32x4){0.f, 0.f, 0.f, 0.f};

    const int ncol0 = w * 32;   // 1x4 wave grid: 64x32 per wave

    __syncthreads();   // single barrier: drains vmcnt (B in LDS, A in regs)

    #pragma unroll
    for (int q = 0; q < 4; ++q) {
        const int kb = q * 64 + lk * 16;
        bf16x8 bfr[2];
        #pragma unroll
        for (int ni = 0; ni < 2; ++ni) {
            int rb = ncol0 + ni * 16 + lrow;
            bfr[ni] = *(const bf16x8*)(smem + rb * 256 + (kb ^ ((rb & 7) << 4)));
        }
        #pragma unroll
        for (int mi = 0; mi < 4; ++mi)
            #pragma unroll
            for (int ni = 0; ni < 2; ++ni)
                acc[mi][ni] = __builtin_amdgcn_mfma_f32_16x16x32_bf16(
                    areg[mi][q], bfr[ni], acc[mi][ni], 0, 0, 0);
    }

    // ---- epilogue ----
    const bool edge = (tc == (tr >> 1));
    const int labRowEnd = labS[rowBase + BM - 1];   // uniform -> s_load
    const int labCol0   = labS[colBase];
    const bool mixed = edge || (labRowEnd == labCol0);

    float4 res;
    if (!mixed) {
        // pure-negative tile (~96%)
        float mx = 0.0f;
        #pragma unroll
        for (int mi = 0; mi < 4; ++mi)
            #pragma unroll
            for (int ni = 0; ni < 2; ++ni)
                #pragma unroll
                for (int r = 0; r < 4; ++r) {
                    float t = fmaxf(acc[mi][ni][r], -0.25f);
                    acc[mi][ni][r] = t;
                    mx = fmaxf(mx, fabsf(t));
                }
        #pragma unroll
        for (int off = 32; off; off >>= 1)
            mx = fmaxf(mx, __shfl_xor(mx, off, 64));
        const float zc = -G2 * mx * mx;
        float sn = 0.f;
        #pragma unroll
        for (int mi = 0; mi < 4; ++mi)
            #pragma unroll
            for (int ni = 0; ni < 2; ++ni)
                #pragma unroll
                for (int r = 0; r < 4; ++r) {
                    float t = acc[mi][ni][r];
                    sn += __builtin_amdgcn_exp2f(fmaf(G2, t * t, zc));
                }
        #pragma unroll
        for (int off = 32; off; off >>= 1)
            sn += __shfl_xor(sn, off, 64);
        res = make_float4(MSENT, 0.f, fmaf(G2, mx * mx, QNEG), sn);
    } else {
        // mixed / edge tile (~4%)
        int lbv[2];
        #pragma unroll
        for (int ni = 0; ni < 2; ++ni)
            lbv[ni] = labS[colBase + ncol0 + ni * 16 + lrow];
        int4 laR[4];
        #pragma unroll
        for (int mi = 0; mi < 4; ++mi)
            laR[mi] = *(const int4*)&labS[rowBase + mi * 16 + lk * 4];

        float minp = 1e30f;    // min s over valid positives
        float mabs = -1.0f;    // max |t| over valid negatives

#define PASS_AB(EDGEF)                                                         \
    _Pragma("unroll")                                                          \
    for (int mi = 0; mi < 4; ++mi) {                                           \
        const int la[4] = {laR[mi].x, laR[mi].y, laR[mi].z, laR[mi].w};        \
        _Pragma("unroll")                                                      \
        for (int ni = 0; ni < 2; ++ni) {                                       \
            _Pragma("unroll")                                                  \
            for (int r = 0; r < 4; ++r) {                                      \
                float s = acc[mi][ni][r];                                      \
                bool pos = (la[r] == lbv[ni]);                                 \
                float t = fmaxf(s, -0.25f);                                    \
                bool valid = true;                                             \
                if (EDGEF) {                                                   \
                    int ig = rowBase + mi * 16 + lk * 4 + r;                   \
                    int jg = colBase + ncol0 + ni * 16 + lrow;                 \
                    valid = (jg > ig);                                         \
                    pos = pos && valid;                                        \
                }                                                              \
                float u = pos ? s : t;                                         \
                minp = fminf(minp, pos ? s : 1e30f);                           \
                bool nm = EDGEF ? (valid && !pos) : !pos;                      \
                mabs = fmaxf(mabs, nm ? fabsf(t) : -1.0f);                     \
                acc[mi][ni][r] = u;                                            \
            }                                                                  \
        }                                                                      \
    }
        if (edge) { PASS_AB(true) } else { PASS_AB(false) }
#undef PASS_AB

        #pragma unroll
        for (int off = 32; off; off >>= 1) {
            minp = fminf(minp, __shfl_xor(minp, off, 64));
            mabs = fmaxf(mabs, __shfl_xor(mabs, off, 64));
        }
        const float Mp = (minp < 2.0f)
            ? fmaf(G2, minp * minp, fmaf(-2.0f * G2, minp, QPOS)) : MSENT;
        const float Mn = (mabs >= 0.0f) ? fmaf(G2, mabs * mabs, QNEG) : MSENT;
        const float qph = QPOS - Mp;
        const float qnh = QNEG - Mn;
        float sp = 0.f, sn = 0.f;

#define PASS_B(EDGEF)                                                          \
    _Pragma("unroll")                                                          \
    for (int mi = 0; mi < 4; ++mi) {                                           \
        const int la[4] = {laR[mi].x, laR[mi].y, laR[mi].z, laR[mi].w};        \
        _Pragma("unroll")                                                      \
        for (int ni = 0; ni < 2; ++ni) {                                       \
            _Pragma("unroll")                                                  \
            for (int r = 0; r < 4; ++r) {                                      \
                float u = acc[mi][ni][r];                                      \
                bool pos = (la[r] == lbv[ni]);                                 \
                float P  = pos ? (-2.0f * G2) : 0.0f;                          \
                float Qh = pos ? qph : qnh;                                    \
                float e = __builtin_amdgcn_exp2f(                              \
                              fmaf(G2, u * u, fmaf(P, u, Qh)));                \
                if (EDGEF) {                                                   \
                    int ig = rowBase + mi * 16 + lk * 4 + r;                   \
                    int jg = colBase + ncol0 + ni * 16 + lrow;                 \
                    e = (jg > ig) ? e : 0.f;                                   \
                }                                                              \
                float ep = pos ? e : 0.f;                                      \
                sp += ep;                                                      \
                sn += (e - ep);                                                \
            }                                                                  \
        }                                                                      \
    }
        if (edge) { PASS_B(true) } else { PASS_B(false) }
#undef PASS_B

        #pragma unroll
        for (int off = 32; off; off >>= 1) {
            sp += __shfl_xor(sp, off, 64);
            sn += __shfl_xor(sn, off, 64);
        }
        res = make_float4(Mp, sp, Mn, sn);
    }
    if (lane == 0) blockRes[bid * 4 + w] = res;
}

// ---- merge helper: (m,s) pairs represent s * 2^m ----
__device__ __forceinline__ void merge2(float& m, float& s, float mo, float so) {
    float M = fmaxf(m, mo);
    s = s * __builtin_amdgcn_exp2f(m - M) + so * __builtin_amdgcn_exp2f(mo - M);
    m = M;
}

// ---- Kernel C1: parallel tree reduce 16640 -> 32 ----
__global__ __launch_bounds__(256)
void reduce_kernel(const float4* __restrict__ in, float4* __restrict__ partial) {
    __shared__ float red[4][4];
    const int tid  = threadIdx.x;
    const int base = blockIdx.x * PERRED;
    float mp = NEGBIG, sp = 0.f, mn = NEGBIG, sn = 0.f;
    for (int i = tid; i < PERRED; i += 256) {
        float4 v = in[base + i];
        merge2(mp, sp, v.x, v.y);
        merge2(mn, sn, v.z, v.w);
    }
    #pragma unroll
    for (int off = 32; off; off >>= 1) {
        float mo = __shfl_xor(mp, off, 64), so = __shfl_xor(sp, off, 64);
        merge2(mp, sp, mo, so);
        float mo2 = __shfl_xor(mn, off, 64), so2 = __shfl_xor(sn, off, 64);
        merge2(mn, sn, mo2, so2);
    }
    const int wv = tid >> 6;
    if ((tid & 63) == 0) {
        red[wv][0] = mp; red[wv][1] = sp; red[wv][2] = mn; red[wv][3] = sn;
    }
    __syncthreads();
    if (tid == 0) {
        mp = red[0][0]; sp = red[0][1]; mn = red[0][2]; sn = red[0][3];
        #pragma unroll
        for (int q = 1; q < 4; ++q) {
            merge2(mp, sp, red[q][0], red[q][1]);
            merge2(mn, sn, red[q][2], red[q][3]);
        }
        partial[blockIdx.x] = make_float4(mp, sp, mn, sn);
    }
}

// ---- Kernel C2: merge 32 partials + softplus ----
__global__ __launch_bounds__(64)
void finalize_kernel(const float4* __restrict__ partial, float* __restrict__ out) {
    const int lane = threadIdx.x;
    float mp = NEGBIG, sp = 0.f, mn = NEGBIG, sn = 0.f;
    if (lane < NRED) {
        float4 v = partial[lane];
        mp = v.x; sp = v.y; mn = v.z; sn = v.w;
    }
    #pragma unroll
    for (int off = 32; off; off >>= 1) {
        float mo = __shfl_xor(mp, off, 64), so = __shfl_xor(sp, off, 64);
        merge2(mp, sp, mo, so);
        float mo2 = __shfl_xor(mn, off, 64), so2 = __shfl_xor(sn, off, 64);
        merge2(mn, sn, mo2, so2);
    }
    if (lane == 0) {
        const double LN2 = 0.6931471805599453;
        double lse_p = ((double)mp + log2((double)sp)) * LN2;
        double lse_n = ((double)mn + log2((double)sn)) * LN2;
        double xx = lse_p + lse_n;
        double r = (xx > 30.0) ? xx : log1p(exp(xx));
        out[0] = (float)r;
    }
}

extern "C" void kernel_launch(void* const* d_in, const int* in_sizes, int n_in,
                              void* d_out, int out_size, void* d_ws, size_t ws_size,
                              hipStream_t stream) {
    const float* f   = (const float*)d_in[0];
    const int*   lab = (const int*)d_in[1];
    float*  out      = (float*)d_out;

    __hip_bfloat16* fhi = (__hip_bfloat16*)d_ws;                      // 2 MB
    int* labS    = (int*)((char*)d_ws + 2u * 1024 * 1024);            // 32 KB
    int* cursor  = (int*)((char*)d_ws + 3u * 1024 * 1024);            // 64*32 ints
    float4* blockRes = (float4*)((char*)d_ws + 4u * 1024 * 1024);     // 16640
    float4* partial  = (float4*)((char*)d_ws + 8u * 1024 * 1024);     // 32

    hist_kernel<<<1, 256, 0, stream>>>(lab, cursor);
    prep_kernel<<<NROW / 4, 256, 0, stream>>>(f, lab, cursor, fhi, labS);
    sim_kernel<<<NTILES, 256, 0, stream>>>(fhi, labS, blockRes);
    reduce_kernel<<<NRED, 256, 0, stream>>>(blockRes, partial);
    finalize_kernel<<<1, 64, 0, stream>>>(partial, out);
}

// Round 11
// 46.743 us; speedup vs baseline: 1.2755x; 1.2755x over previous
//
#include <hip/hip_runtime.h>
#include <hip/hip_bf16.h>
#include <math.h>

#define NROW 8192
#define DIM  128
#define BM   64
#define BN   128
#define NBLK   2080         // sum_{tc<64} (tc+1); each block = col-panel + 2 row-tiles
#define NTILES (NBLK * 2)   // 4160
#define NT4    (NTILES * 4) // per-wave results = 16640 = 32 * 520
#define NRED   32
#define PERRED (NT4 / NRED) // 520

typedef __bf16 bf16x8 __attribute__((ext_vector_type(8)));
typedef float  f32x4  __attribute__((ext_vector_type(4)));

#define G2     369.3299304675746f   /* 256 * log2(e): logits in base-2 */
#define QPOS   (0.9375f * G2)       /* xp = G2*s^2 - 2*G2*s + QPOS      */
#define QNEG   (-0.0625f * G2)      /* xn = G2*t^2 + QNEG, t=max(s,-.25)*/
#define NEGBIG (-3.0e38f)
#define MSENT  (-4000.0f)           /* empty-class sentinel */
#define CSTR   32                   /* cursor stride: 1 counter / 128B  */

// ---- Kernel H: label histogram + exclusive prefix -> padded cursor ----
__global__ __launch_bounds__(256)
void hist_kernel(const int* __restrict__ lab, int* __restrict__ cursor) {
    __shared__ int h[4][64];
    const int tid  = threadIdx.x;
    const int w    = tid >> 6;
    const int lane = tid & 63;
    h[w][lane] = 0;
    __syncthreads();
    for (int i = tid; i < NROW; i += 256)
        atomicAdd(&h[w][lab[i]], 1);
    __syncthreads();
    if (tid < 64) {
        int tot = h[0][tid] + h[1][tid] + h[2][tid] + h[3][tid];
        int v = tot;
        #pragma unroll
        for (int off = 1; off < 64; off <<= 1) {
            int u = __shfl_up(v, off, 64);
            if (tid >= off) v += u;
        }
        cursor[tid * CSTR] = v - tot;   // exclusive prefix, cacheline-padded
    }
}

// ---- Kernel A: normalize rows -> bf16, scattered into label-sorted order ----
__global__ __launch_bounds__(256)
void prep_kernel(const float* __restrict__ f, const int* __restrict__ lab,
                 int* __restrict__ cursor,
                 __hip_bfloat16* __restrict__ fhi, int* __restrict__ labS) {
    int row  = blockIdx.x * 4 + (threadIdx.x >> 6);
    int lane = threadIdx.x & 63;
    float2 v = ((const float2*)(f + (size_t)row * DIM))[lane];
    float ss = v.x * v.x + v.y * v.y;
    #pragma unroll
    for (int off = 32; off; off >>= 1) ss += __shfl_xor(ss, off, 64);
    float inv = 1.0f / fmaxf(sqrtf(ss), 1e-12f);
    int l = lab[row];
    int dest = 0;
    if (lane == 0) dest = atomicAdd(&cursor[l * CSTR], 1);
    dest = __shfl(dest, 0, 64);
    __hip_bfloat162 hv;
    hv.x = __float2bfloat16(v.x * inv);
    hv.y = __float2bfloat16(v.y * inv);
    ((__hip_bfloat162*)(fhi + (size_t)dest * DIM))[lane] = hv;
    if (lane == 0) labS[dest] = l;
}

// ---- Kernel B: col-panel-resident sim; ONE barrier per block ----
__global__ __launch_bounds__(256, 2)
void sim_kernel(const __hip_bfloat16* __restrict__ fhi,
                const int* __restrict__ labS,
                float4* __restrict__ blockRes) {
    const int tid  = threadIdx.x;
    const int w    = tid >> 6;
    const int lane = tid & 63;
    const int lrow = lane & 15;
    const int lk   = lane >> 4;

    // bid -> (tc, chunk): standard triangular decode, chunk in 0..tc
    int bid = blockIdx.x;
    int tc = (int)((sqrtf(8.f * (float)bid + 1.f) - 1.f) * 0.5f);
    if (tc > 63) tc = 63;
    while (tc > 0 && bid < (tc * (tc + 1)) / 2) --tc;
    while (bid >= ((tc + 1) * (tc + 2)) / 2) ++tc;
    const int chunk = bid - (tc * (tc + 1)) / 2;          // 0..tc
    const bool edge = (chunk == tc);                      // both tiles straddle diag

    const int colBase  = tc * BN;
    const int rowBase0 = (2 * chunk) * BM;
    const int rowBase1 = rowBase0 + BM;

    // LDS: B[128][256B] = 32KB resident; A0[64][256B], A1[64][256B] 16KB each
    __shared__ __align__(16) char smem[64 * 1024];
    char* Bs = smem;
    char* A0 = smem + 32 * 1024;
    char* A1 = smem + 48 * 1024;

    const int rsub4 = lane >> 4;              // row within 4-row segment
    const int col16 = (lane & 15) << 4;       // 16B slot within 256B row

    // ---- stage B panel: 32 x 1KB segments (8/wave) ----
    #pragma unroll
    for (int t = 0; t < 8; ++t) {
        int seg  = w * 8 + t;                 // 0..31
        int brow = seg * 4 + rsub4;           // 0..127
        const char* g = (const char*)fhi + (size_t)(colBase + brow) * 256
                      + (col16 ^ ((brow & 7) << 4));
        __builtin_amdgcn_global_load_lds(
            (const __attribute__((address_space(1))) void*)g,
            (__attribute__((address_space(3))) void*)(Bs + seg * 1024), 16, 0, 0);
    }
    // ---- stage A tiles (dbuf): 16 x 1KB segments each (4/wave) ----
    #pragma unroll
    for (int t = 0; t < 4; ++t) {
        int seg  = w * 4 + t;                 // 0..15
        int arow = seg * 4 + rsub4;           // 0..63
        int swz  = (col16 ^ ((arow & 7) << 4));
        const char* g0 = (const char*)fhi + (size_t)(rowBase0 + arow) * 256 + swz;
        const char* g1 = (const char*)fhi + (size_t)(rowBase1 + arow) * 256 + swz;
        __builtin_amdgcn_global_load_lds(
            (const __attribute__((address_space(1))) void*)g0,
            (__attribute__((address_space(3))) void*)(A0 + seg * 1024), 16, 0, 0);
        __builtin_amdgcn_global_load_lds(
            (const __attribute__((address_space(1))) void*)g1,
            (__attribute__((address_space(3))) void*)(A1 + seg * 1024), 16, 0, 0);
    }

    // hoist per-tile uniform label probes (hide under drain)
    const int labCol0 = labS[colBase];
    const int labRE0  = labS[rowBase0 + BM - 1];
    const int labRE1  = labS[rowBase1 + BM - 1];

    const int ncol0 = w * 32;   // 1x4 wave grid: 64x32 per wave

    __syncthreads();   // single barrier: drains all 16 loads (B, A0, A1)

    f32x4 acc[4][2];

    #pragma unroll
    for (int ti = 0; ti < 2; ++ti) {
        const char* As      = ti ? A1 : A0;
        const int   rowBase = ti ? rowBase1 : rowBase0;
        const int   labRE   = ti ? labRE1 : labRE0;

        #pragma unroll
        for (int mi = 0; mi < 4; ++mi)
            #pragma unroll
            for (int ni = 0; ni < 2; ++ni) acc[mi][ni] = (f32x4){0.f, 0.f, 0.f, 0.f};

        #pragma unroll
        for (int q = 0; q < 4; ++q) {
            const int kb = q * 64 + lk * 16;
            bf16x8 bfr[2];
            #pragma unroll
            for (int ni = 0; ni < 2; ++ni) {
                int rb = ncol0 + ni * 16 + lrow;
                bfr[ni] = *(const bf16x8*)(Bs + rb * 256 + (kb ^ ((rb & 7) << 4)));
            }
            #pragma unroll
            for (int mi = 0; mi < 4; ++mi) {
                int ra = mi * 16 + lrow;
                bf16x8 afr = *(const bf16x8*)(As + ra * 256 + (kb ^ ((ra & 7) << 4)));
                #pragma unroll
                for (int ni = 0; ni < 2; ++ni)
                    acc[mi][ni] = __builtin_amdgcn_mfma_f32_16x16x32_bf16(
                        afr, bfr[ni], acc[mi][ni], 0, 0, 0);
            }
        }

        // ---- epilogue (register/shuffle only, no barrier) ----
        const bool mixed = edge || (labRE == labCol0);
        float4 res;
        if (!mixed) {
            // pure-negative tile (~96%)
            float mx = 0.0f;
            #pragma unroll
            for (int mi = 0; mi < 4; ++mi)
                #pragma unroll
                for (int ni = 0; ni < 2; ++ni)
                    #pragma unroll
                    for (int r = 0; r < 4; ++r) {
                        float t = fmaxf(acc[mi][ni][r], -0.25f);
                        acc[mi][ni][r] = t;
                        mx = fmaxf(mx, fabsf(t));
                    }
            #pragma unroll
            for (int off = 32; off; off >>= 1)
                mx = fmaxf(mx, __shfl_xor(mx, off, 64));
            const float zc = -G2 * mx * mx;
            float sn = 0.f;
            #pragma unroll
            for (int mi = 0; mi < 4; ++mi)
                #pragma unroll
                for (int ni = 0; ni < 2; ++ni)
                    #pragma unroll
                    for (int r = 0; r < 4; ++r) {
                        float t = acc[mi][ni][r];
                        sn += __builtin_amdgcn_exp2f(fmaf(G2, t * t, zc));
                    }
            #pragma unroll
            for (int off = 32; off; off >>= 1)
                sn += __shfl_xor(sn, off, 64);
            res = make_float4(MSENT, 0.f, fmaf(G2, mx * mx, QNEG), sn);
        } else {
            // mixed / edge tile (~4%)
            int lbv[2];
            #pragma unroll
            for (int ni = 0; ni < 2; ++ni)
                lbv[ni] = labS[colBase + ncol0 + ni * 16 + lrow];
            int4 laR[4];
            #pragma unroll
            for (int mi = 0; mi < 4; ++mi)
                laR[mi] = *(const int4*)&labS[rowBase + mi * 16 + lk * 4];

            float minp = 1e30f;    // min s over valid positives
            float mabs = -1.0f;    // max |t| over valid negatives

#define PASS_AB(EDGEF)                                                         \
    _Pragma("unroll")                                                          \
    for (int mi = 0; mi < 4; ++mi) {                                           \
        const int la[4] = {laR[mi].x, laR[mi].y, laR[mi].z, laR[mi].w};        \
        _Pragma("unroll")                                                      \
        for (int ni = 0; ni < 2; ++ni) {                                       \
            _Pragma("unroll")                                                  \
            for (int r = 0; r < 4; ++r) {                                      \
                float s = acc[mi][ni][r];                                      \
                bool pos = (la[r] == lbv[ni]);                                 \
                float t = fmaxf(s, -0.25f);                                    \
                bool valid = true;                                             \
                if (EDGEF) {                                                   \
                    int ig = rowBase + mi * 16 + lk * 4 + r;                   \
                    int jg = colBase + ncol0 + ni * 16 + lrow;                 \
                    valid = (jg > ig);                                         \
                    pos = pos && valid;                                        \
                }                                                              \
                float u = pos ? s : t;                                         \
                minp = fminf(minp, pos ? s : 1e30f);                           \
                bool nm = EDGEF ? (valid && !pos) : !pos;                      \
                mabs = fmaxf(mabs, nm ? fabsf(t) : -1.0f);                     \
                acc[mi][ni][r] = u;                                            \
            }                                                                  \
        }                                                                      \
    }
            if (edge) { PASS_AB(true) } else { PASS_AB(false) }
#undef PASS_AB

            #pragma unroll
            for (int off = 32; off; off >>= 1) {
                minp = fminf(minp, __shfl_xor(minp, off, 64));
                mabs = fmaxf(mabs, __shfl_xor(mabs, off, 64));
            }
            const float Mp = (minp < 2.0f)
                ? fmaf(G2, minp * minp, fmaf(-2.0f * G2, minp, QPOS)) : MSENT;
            const float Mn = (mabs >= 0.0f) ? fmaf(G2, mabs * mabs, QNEG) : MSENT;
            const float qph = QPOS - Mp;
            const float qnh = QNEG - Mn;
            float sp = 0.f, sn = 0.f;

#define PASS_B(EDGEF)                                                          \
    _Pragma("unroll")                                                          \
    for (int mi = 0; mi < 4; ++mi) {                                           \
        const int la[4] = {laR[mi].x, laR[mi].y, laR[mi].z, laR[mi].w};        \
        _Pragma("unroll")                                                      \
        for (int ni = 0; ni < 2; ++ni) {                                       \
            _Pragma("unroll")                                                  \
            for (int r = 0; r < 4; ++r) {                                      \
                float u = acc[mi][ni][r];                                      \
                bool pos = (la[r] == lbv[ni]);                                 \
                float P  = pos ? (-2.0f * G2) : 0.0f;                          \
                float Qh = pos ? qph : qnh;                                    \
                float e = __builtin_amdgcn_exp2f(                              \
                              fmaf(G2, u * u, fmaf(P, u, Qh)));                \
                if (EDGEF) {                                                   \
                    int ig = rowBase + mi * 16 + lk * 4 + r;                   \
                    int jg = colBase + ncol0 + ni * 16 + lrow;                 \
                    e = (jg > ig) ? e : 0.f;                                   \
                }                                                              \
                float ep = pos ? e : 0.f;                                      \
                sp += ep;                                                      \
                sn += (e - ep);                                                \
            }                                                                  \
        }                                                                      \
    }
            if (edge) { PASS_B(true) } else { PASS_B(false) }
#undef PASS_B

            #pragma unroll
            for (int off = 32; off; off >>= 1) {
                sp += __shfl_xor(sp, off, 64);
                sn += __shfl_xor(sn, off, 64);
            }
            res = make_float4(Mp, sp, Mn, sn);
        }
        if (lane == 0) blockRes[(bid * 2 + ti) * 4 + w] = res;
    }
}

// ---- merge helper: (m,s) pairs represent s * 2^m ----
__device__ __forceinline__ void merge2(float& m, float& s, float mo, float so) {
    float M = fmaxf(m, mo);
    s = s * __builtin_amdgcn_exp2f(m - M) + so * __builtin_amdgcn_exp2f(mo - M);
    m = M;
}

// ---- Kernel C1: parallel tree reduce 16640 -> 32 ----
__global__ __launch_bounds__(256)
void reduce_kernel(const float4* __restrict__ in, float4* __restrict__ partial) {
    __shared__ float red[4][4];
    const int tid  = threadIdx.x;
    const int base = blockIdx.x * PERRED;
    float mp = NEGBIG, sp = 0.f, mn = NEGBIG, sn = 0.f;
    for (int i = tid; i < PERRED; i += 256) {
        float4 v = in[base + i];
        merge2(mp, sp, v.x, v.y);
        merge2(mn, sn, v.z, v.w);
    }
    #pragma unroll
    for (int off = 32; off; off >>= 1) {
        float mo = __shfl_xor(mp, off, 64), so = __shfl_xor(sp, off, 64);
        merge2(mp, sp, mo, so);
        float mo2 = __shfl_xor(mn, off, 64), so2 = __shfl_xor(sn, off, 64);
        merge2(mn, sn, mo2, so2);
    }
    const int wv = tid >> 6;
    if ((tid & 63) == 0) {
        red[wv][0] = mp; red[wv][1] = sp; red[wv][2] = mn; red[wv][3] = sn;
    }
    __syncthreads();
    if (tid == 0) {
        mp = red[0][0]; sp = red[0][1]; mn = red[0][2]; sn = red[0][3];
        #pragma unroll
        for (int q = 1; q < 4; ++q) {
            merge2(mp, sp, red[q][0], red[q][1]);
            merge2(mn, sn, red[q][2], red[q][3]);
        }
        partial[blockIdx.x] = make_float4(mp, sp, mn, sn);
    }
}

// ---- Kernel C2: merge 32 partials + softplus ----
__global__ __launch_bounds__(64)
void finalize_kernel(const float4* __restrict__ partial, float* __restrict__ out) {
    const int lane = threadIdx.x;
    float mp = NEGBIG, sp = 0.f, mn = NEGBIG, sn = 0.f;
    if (lane < NRED) {
        float4 v = partial[lane];
        mp = v.x; sp = v.y; mn = v.z; sn = v.w;
    }
    #pragma unroll
    for (int off = 32; off; off >>= 1) {
        float mo = __shfl_xor(mp, off, 64), so = __shfl_xor(sp, off, 64);
        merge2(mp, sp, mo, so);
        float mo2 = __shfl_xor(mn, off, 64), so2 = __shfl_xor(sn, off, 64);
        merge2(mn, sn, mo2, so2);
    }
    if (lane == 0) {
        const double LN2 = 0.6931471805599453;
        double lse_p = ((double)mp + log2((double)sp)) * LN2;
        double lse_n = ((double)mn + log2((double)sn)) * LN2;
        double xx = lse_p + lse_n;
        double r = (xx > 30.0) ? xx : log1p(exp(xx));
        out[0] = (float)r;
    }
}

extern "C" void kernel_launch(void* const* d_in, const int* in_sizes, int n_in,
                              void* d_out, int out_size, void* d_ws, size_t ws_size,
                              hipStream_t stream) {
    const float* f   = (const float*)d_in[0];
    const int*   lab = (const int*)d_in[1];
    float*  out      = (float*)d_out;

    __hip_bfloat16* fhi = (__hip_bfloat16*)d_ws;                      // 2 MB
    int* labS    = (int*)((char*)d_ws + 2u * 1024 * 1024);            // 32 KB
    int* cursor  = (int*)((char*)d_ws + 3u * 1024 * 1024);            // 64*32 ints
    float4* blockRes = (float4*)((char*)d_ws + 4u * 1024 * 1024);     // 16640
    float4* partial  = (float4*)((char*)d_ws + 8u * 1024 * 1024);     // 32

    hist_kernel<<<1, 256, 0, stream>>>(lab, cursor);
    prep_kernel<<<NROW / 4, 256, 0, stream>>>(f, lab, cursor, fhi, labS);
    sim_kernel<<<NBLK, 256, 0, stream>>>(fhi, labS, blockRes);
    reduce_kernel<<<NRED, 256, 0, stream>>>(blockRes, partial);
    finalize_kernel<<<1, 64, 0, stream>>>(partial, out);
}

// Round 12
// 45.425 us; speedup vs baseline: 1.3125x; 1.0290x over previous
//
#include <hip/hip_runtime.h>
#include <hip/hip_bf16.h>
#include <math.h>

#define NROW 8192
#define DIM  128
#define BT   128            // square tile
#define NT   (NROW / BT)    // 64
#define NBLK ((NT * (NT + 1)) / 2)   // 2080
#define NT4  (NBLK * 8)     // per-wave results = 16640 = 32 * 520
#define NRED   32
#define PERRED (NT4 / NRED) // 520

typedef __bf16 bf16x8 __attribute__((ext_vector_type(8)));
typedef float  f32x4  __attribute__((ext_vector_type(4)));

#define G2     369.3299304675746f   /* 256 * log2(e): logits in base-2 */
#define QPOS   (0.9375f * G2)       /* xp = G2*s^2 - 2*G2*s + QPOS      */
#define QNEG   (-0.0625f * G2)      /* xn = G2*t^2 + QNEG, t=max(s,-.25)*/
#define NEGBIG (-3.0e38f)
#define MSENT  (-4000.0f)           /* empty-class sentinel */

// ---- Kernel A: normalize rows -> bf16 (coalesced, no sort) ----
__global__ __launch_bounds__(256)
void prep_kernel(const float* __restrict__ f, __hip_bfloat16* __restrict__ fhi) {
    int row  = blockIdx.x * 4 + (threadIdx.x >> 6);
    int lane = threadIdx.x & 63;
    float2 v = ((const float2*)(f + (size_t)row * DIM))[lane];
    float ss = v.x * v.x + v.y * v.y;
    #pragma unroll
    for (int off = 32; off; off >>= 1) ss += __shfl_xor(ss, off, 64);
    float inv = 1.0f / fmaxf(sqrtf(ss), 1e-12f);
    __hip_bfloat162 hv;
    hv.x = __float2bfloat16(v.x * inv);
    hv.y = __float2bfloat16(v.y * inv);
    ((__hip_bfloat162*)(fhi + (size_t)row * DIM))[lane] = hv;
}

// ---- Kernel B: 128x128 tile, 8 waves, one-shot K=128 stage, ONE barrier ----
__global__ __launch_bounds__(512, 4)
void sim_kernel(const __hip_bfloat16* __restrict__ fhi,
                const int* __restrict__ lab,
                float4* __restrict__ blockRes) {
    const int tid  = threadIdx.x;
    const int w    = tid >> 6;     // 0..7
    const int lane = tid & 63;
    const int lrow = lane & 15;
    const int lk   = lane >> 4;

    // triangular decode: bid -> (tr, tc), tc >= tr (64x64 tile grid)
    int bid = blockIdx.x;
    int tr = (int)((129.0f - sqrtf(16641.0f - 8.0f * (float)bid)) * 0.5f);
    while (tr > 0 && bid < tr * NT - (tr * (tr - 1)) / 2) --tr;
    while (bid >= (tr + 1) * NT - ((tr + 1) * tr) / 2) ++tr;
    const int tc = tr + (bid - (tr * NT - (tr * (tr - 1)) / 2));

    const int rowBase = tr * BT;
    const int colBase = tc * BT;
    const bool edge = (tr == tc);

    __shared__ __align__(16) char smem[64 * 1024];  // A[128][256B] + B[128][256B]
    __shared__ int labA[BT];
    __shared__ int labB[BT];
    char* As = smem;
    char* Bs = smem + 32 * 1024;

    if (tid < BT)            labA[tid] = lab[rowBase + tid];
    else if (tid < 2 * BT)   labB[tid - BT] = lab[colBase + (tid - BT)];

    const int rsub4 = lane >> 4;              // row within 4-row segment
    const int col16 = (lane & 15) << 4;       // 16B slot within 256B row

    // ---- stage 64KB: 64 x 1KB segments, 8 per wave ----
    #pragma unroll
    for (int t = 0; t < 8; ++t) {
        int seg = w * 8 + t;                  // 0..63
        int arr = seg >> 5;                   // 0:A 1:B
        int s32 = seg & 31;
        int row = s32 * 4 + rsub4;            // 0..127
        const char* g = (const char*)fhi
            + (size_t)((arr ? colBase : rowBase) + row) * 256
            + (col16 ^ ((row & 7) << 4));     // pre-swizzled source (rule 21)
        char* ldsb = (arr ? Bs : As) + s32 * 1024;
        __builtin_amdgcn_global_load_lds(
            (const __attribute__((address_space(1))) void*)g,
            (__attribute__((address_space(3))) void*)ldsb, 16, 0, 0);
    }

    f32x4 acc[4][2];
    #pragma unroll
    for (int mi = 0; mi < 4; ++mi)
        #pragma unroll
        for (int ni = 0; ni < 2; ++ni) acc[mi][ni] = (f32x4){0.f, 0.f, 0.f, 0.f};

    const int mrow0 = (w >> 2) * 64;   // 2x4 wave grid: 64x32 per wave
    const int ncol0 = (w & 3) * 32;

    __syncthreads();   // single barrier: drains all 16 loads + label writes

    #pragma unroll
    for (int q = 0; q < 4; ++q) {
        const int kb = q * 64 + lk * 16;
        bf16x8 bfr[2];
        #pragma unroll
        for (int ni = 0; ni < 2; ++ni) {
            int rb = ncol0 + ni * 16 + lrow;
            bfr[ni] = *(const bf16x8*)(Bs + rb * 256 + (kb ^ ((rb & 7) << 4)));
        }
        #pragma unroll
        for (int mi = 0; mi < 4; ++mi) {
            int ra = mrow0 + mi * 16 + lrow;
            bf16x8 afr = *(const bf16x8*)(As + ra * 256 + (kb ^ ((ra & 7) << 4)));
            #pragma unroll
            for (int ni = 0; ni < 2; ++ni)
                acc[mi][ni] = __builtin_amdgcn_mfma_f32_16x16x32_bf16(
                    afr, bfr[ni], acc[mi][ni], 0, 0, 0);
        }
    }

    // ---- lean general epilogue (monotone logits: track extremes only) ----
    int lbv[2];
    #pragma unroll
    for (int ni = 0; ni < 2; ++ni) lbv[ni] = labB[ncol0 + ni * 16 + lrow];
    int4 laR[4];
    #pragma unroll
    for (int mi = 0; mi < 4; ++mi)
        laR[mi] = *(const int4*)&labA[mrow0 + mi * 16 + lk * 4];

    float minp = 1e30f;    // min s over valid positives (xp decreasing in s)
    float mabs = -1.0f;    // max |t| over valid negatives (xn increasing in |t|)

#define PASS_A(EDGEF)                                                          \
    _Pragma("unroll")                                                          \
    for (int mi = 0; mi < 4; ++mi) {                                           \
        const int la[4] = {laR[mi].x, laR[mi].y, laR[mi].z, laR[mi].w};        \
        _Pragma("unroll")                                                      \
        for (int ni = 0; ni < 2; ++ni) {                                       \
            _Pragma("unroll")                                                  \
            for (int r = 0; r < 4; ++r) {                                      \
                float s = acc[mi][ni][r];                                      \
                bool pos = (la[r] == lbv[ni]);                                 \
                float t = fmaxf(s, -0.25f);                                    \
                bool valid = true;                                             \
                if (EDGEF) {                                                   \
                    int il = mrow0 + mi * 16 + lk * 4 + r;                     \
                    int jl = ncol0 + ni * 16 + lrow;                           \
                    valid = (jl > il);                                         \
                    pos = pos && valid;                                        \
                }                                                              \
                float u = pos ? s : t;                                         \
                minp = fminf(minp, pos ? s : 1e30f);                           \
                bool nm = EDGEF ? (valid && !pos) : !pos;                      \
                mabs = fmaxf(mabs, nm ? fabsf(t) : -1.0f);                     \
                acc[mi][ni][r] = u;                                            \
            }                                                                  \
        }                                                                      \
    }
    if (edge) { PASS_A(true) } else { PASS_A(false) }
#undef PASS_A

    #pragma unroll
    for (int off = 32; off; off >>= 1) {
        minp = fminf(minp, __shfl_xor(minp, off, 64));
        mabs = fmaxf(mabs, __shfl_xor(mabs, off, 64));
    }
    const float Mp = (minp < 2.0f)
        ? fmaf(G2, minp * minp, fmaf(-2.0f * G2, minp, QPOS)) : MSENT;
    const float Mn = (mabs >= 0.0f) ? fmaf(G2, mabs * mabs, QNEG) : MSENT;
    const float qph = QPOS - Mp;
    const float qnh = QNEG - Mn;
    float sp = 0.f, sn = 0.f;

#define PASS_B(EDGEF)                                                          \
    _Pragma("unroll")                                                          \
    for (int mi = 0; mi < 4; ++mi) {                                           \
        const int la[4] = {laR[mi].x, laR[mi].y, laR[mi].z, laR[mi].w};        \
        _Pragma("unroll")                                                      \
        for (int ni = 0; ni < 2; ++ni) {                                       \
            _Pragma("unroll")                                                  \
            for (int r = 0; r < 4; ++r) {                                      \
                float u = acc[mi][ni][r];                                      \
                bool pos = (la[r] == lbv[ni]);                                 \
                float P  = pos ? (-2.0f * G2) : 0.0f;                          \
                float Qh = pos ? qph : qnh;                                    \
                float e = __builtin_amdgcn_exp2f(                              \
                              fmaf(G2, u * u, fmaf(P, u, Qh)));                \
                if (EDGEF) {                                                   \
                    int il = mrow0 + mi * 16 + lk * 4 + r;                     \
                    int jl = ncol0 + ni * 16 + lrow;                           \
                    e = (jl > il) ? e : 0.f;                                   \
                }                                                              \
                float ep = pos ? e : 0.f;                                      \
                sp += ep;                                                      \
                sn += (e - ep);                                                \
            }                                                                  \
        }                                                                      \
    }
    if (edge) { PASS_B(true) } else { PASS_B(false) }
#undef PASS_B

    #pragma unroll
    for (int off = 32; off; off >>= 1) {
        sp += __shfl_xor(sp, off, 64);
        sn += __shfl_xor(sn, off, 64);
    }
    if (lane == 0) blockRes[bid * 8 + w] = make_float4(Mp, sp, Mn, sn);
}

// ---- merge helper: (m,s) pairs represent s * 2^m ----
__device__ __forceinline__ void merge2(float& m, float& s, float mo, float so) {
    float M = fmaxf(m, mo);
    s = s * __builtin_amdgcn_exp2f(m - M) + so * __builtin_amdgcn_exp2f(mo - M);
    m = M;
}

// ---- Kernel C1: parallel tree reduce 16640 -> 32 ----
__global__ __launch_bounds__(256)
void reduce_kernel(const float4* __restrict__ in, float4* __restrict__ partial) {
    __shared__ float red[4][4];
    const int tid  = threadIdx.x;
    const int base = blockIdx.x * PERRED;
    float mp = NEGBIG, sp = 0.f, mn = NEGBIG, sn = 0.f;
    for (int i = tid; i < PERRED; i += 256) {
        float4 v = in[base + i];
        merge2(mp, sp, v.x, v.y);
        merge2(mn, sn, v.z, v.w);
    }
    #pragma unroll
    for (int off = 32; off; off >>= 1) {
        float mo = __shfl_xor(mp, off, 64), so = __shfl_xor(sp, off, 64);
        merge2(mp, sp, mo, so);
        float mo2 = __shfl_xor(mn, off, 64), so2 = __shfl_xor(sn, off, 64);
        merge2(mn, sn, mo2, so2);
    }
    const int wv = tid >> 6;
    if ((tid & 63) == 0) {
        red[wv][0] = mp; red[wv][1] = sp; red[wv][2] = mn; red[wv][3] = sn;
    }
    __syncthreads();
    if (tid == 0) {
        mp = red[0][0]; sp = red[0][1]; mn = red[0][2]; sn = red[0][3];
        #pragma unroll
        for (int q = 1; q < 4; ++q) {
            merge2(mp, sp, red[q][0], red[q][1]);
            merge2(mn, sn, red[q][2], red[q][3]);
        }
        partial[blockIdx.x] = make_float4(mp, sp, mn, sn);
    }
}

// ---- Kernel C2: merge 32 partials + softplus ----
__global__ __launch_bounds__(64)
void finalize_kernel(const float4* __restrict__ partial, float* __restrict__ out) {
    const int lane = threadIdx.x;
    float mp = NEGBIG, sp = 0.f, mn = NEGBIG, sn = 0.f;
    if (lane < NRED) {
        float4 v = partial[lane];
        mp = v.x; sp = v.y; mn = v.z; sn = v.w;
    }
    #pragma unroll
    for (int off = 32; off; off >>= 1) {
        float mo = __shfl_xor(mp, off, 64), so = __shfl_xor(sp, off, 64);
        merge2(mp, sp, mo, so);
        float mo2 = __shfl_xor(mn, off, 64), so2 = __shfl_xor(sn, off, 64);
        merge2(mn, sn, mo2, so2);
    }
    if (lane == 0) {
        const double LN2 = 0.6931471805599453;
        double lse_p = ((double)mp + log2((double)sp)) * LN2;
        double lse_n = ((double)mn + log2((double)sn)) * LN2;
        double xx = lse_p + lse_n;
        double r = (xx > 30.0) ? xx : log1p(exp(xx));
        out[0] = (float)r;
    }
}

extern "C" void kernel_launch(void* const* d_in, const int* in_sizes, int n_in,
                              void* d_out, int out_size, void* d_ws, size_t ws_size,
                              hipStream_t stream) {
    const float* f   = (const float*)d_in[0];
    const int*   lab = (const int*)d_in[1];
    float*  out      = (float*)d_out;

    __hip_bfloat16* fhi = (__hip_bfloat16*)d_ws;                      // 2 MB
    float4* blockRes = (float4*)((char*)d_ws + 4u * 1024 * 1024);     // 16640
    float4* partial  = (float4*)((char*)d_ws + 8u * 1024 * 1024);     // 32

    prep_kernel<<<NROW / 4, 256, 0, stream>>>(f, fhi);
    sim_kernel<<<NBLK, 512, 0, stream>>>(fhi, lab, blockRes);
    reduce_kernel<<<NRED, 256, 0, stream>>>(blockRes, partial);
    finalize_kernel<<<1, 64, 0, stream>>>(partial, out);
}